// Round 1
// baseline (808.215 us; speedup 1.0000x reference)
//
#include <hip/hip_runtime.h>
#include <math.h>

#define NFEAT 128
#define NHID  24
#define NCLS  16

// ---------------------------------------------------------------------------
// K1: degree count by dst (row 0 of edge_index), float atomics
__global__ void deg_kernel(const int* __restrict__ ei, float* __restrict__ deg, int E) {
    int e = blockIdx.x * blockDim.x + threadIdx.x;
    if (e < E) atomicAdd(&deg[ei[e]], 1.0f);
}

// K2: dinv = rsqrt(deg + 1)   (the +1 is the self loop)
__global__ void dinv_kernel(float* __restrict__ deg, int N) {
    int i = blockIdx.x * blockDim.x + threadIdx.x;
    if (i < N) deg[i] = rsqrtf(deg[i] + 1.0f);
}

// K3: h1 = x @ W1   (N x 128) @ (128 x 24); W1 staged in LDS (12 KB)
__global__ void __launch_bounds__(256) gemm1_kernel(const float* __restrict__ x,
                                                    const float* __restrict__ W1,
                                                    float* __restrict__ h1, int N) {
    __shared__ float w[NFEAT * NHID];
    for (int i = threadIdx.x; i < NFEAT * NHID; i += blockDim.x) w[i] = W1[i];
    __syncthreads();
    int row = blockIdx.x * blockDim.x + threadIdx.x;
    if (row >= N) return;
    float acc[NHID];
#pragma unroll
    for (int j = 0; j < NHID; j++) acc[j] = 0.0f;
    const float4* xr = (const float4*)(x + (size_t)row * NFEAT);
    for (int k4 = 0; k4 < NFEAT / 4; k4++) {
        float4 v = xr[k4];
        const float* wr = &w[k4 * 4 * NHID];
#pragma unroll
        for (int j = 0; j < NHID; j++) acc[j] += v.x * wr[j];
#pragma unroll
        for (int j = 0; j < NHID; j++) acc[j] += v.y * wr[NHID + j];
#pragma unroll
        for (int j = 0; j < NHID; j++) acc[j] += v.z * wr[2 * NHID + j];
#pragma unroll
        for (int j = 0; j < NHID; j++) acc[j] += v.w * wr[3 * NHID + j];
    }
    float* o = h1 + (size_t)row * NHID;
#pragma unroll
    for (int j = 0; j < NHID; j++) o[j] = acc[j];
}

// K4/K6: edge aggregation, one thread per (edge, feature)
//   agg[dst*FD + f] += dinv[dst]*dinv[src] * h[src*FD + f]
template <int FD>
__global__ void __launch_bounds__(256) agg_kernel(const int* __restrict__ ei,
                                                  const float* __restrict__ dinv,
                                                  const float* __restrict__ h,
                                                  float* __restrict__ agg, int E) {
    int idx = blockIdx.x * blockDim.x + threadIdx.x;   // < E*FD <= 76.8M, fits int
    if (idx >= E * FD) return;
    int e = idx / FD;
    int f = idx - e * FD;
    int dst = ei[e];
    int src = ei[E + e];
    float nm = dinv[dst] * dinv[src];
    atomicAdd(&agg[dst * FD + f], nm * h[src * FD + f]);
}

// K5: hrelu = relu(agg1 + dinv^2*h1 + b1);  h2 = hrelu @ W2  (24 -> 16)
__global__ void __launch_bounds__(256) fuse2_kernel(const float* __restrict__ agg1,
                                                    const float* __restrict__ h1,
                                                    const float* __restrict__ dinv,
                                                    const float* __restrict__ W2,
                                                    const float* __restrict__ b1,
                                                    float* __restrict__ h2, int N) {
    __shared__ float w[NHID * NCLS];
    __shared__ float bs[NHID];
    for (int i = threadIdx.x; i < NHID * NCLS; i += blockDim.x) w[i] = W2[i];
    for (int i = threadIdx.x; i < NHID; i += blockDim.x) bs[i] = b1[i];
    __syncthreads();
    int row = blockIdx.x * blockDim.x + threadIdx.x;
    if (row >= N) return;
    float di = dinv[row];
    float d2 = di * di;
    float hr[NHID];
    const float4* a4 = (const float4*)(agg1 + (size_t)row * NHID);
    const float4* h4 = (const float4*)(h1 + (size_t)row * NHID);
#pragma unroll
    for (int q = 0; q < NHID / 4; q++) {
        float4 a = a4[q];
        float4 hv = h4[q];
        hr[4 * q + 0] = fmaxf(a.x + d2 * hv.x + bs[4 * q + 0], 0.0f);
        hr[4 * q + 1] = fmaxf(a.y + d2 * hv.y + bs[4 * q + 1], 0.0f);
        hr[4 * q + 2] = fmaxf(a.z + d2 * hv.z + bs[4 * q + 2], 0.0f);
        hr[4 * q + 3] = fmaxf(a.w + d2 * hv.w + bs[4 * q + 3], 0.0f);
    }
    float acc[NCLS];
#pragma unroll
    for (int j = 0; j < NCLS; j++) acc[j] = 0.0f;
#pragma unroll
    for (int k = 0; k < NHID; k++) {
#pragma unroll
        for (int j = 0; j < NCLS; j++) acc[j] += hr[k] * w[k * NCLS + j];
    }
    float* o = h2 + (size_t)row * NCLS;
#pragma unroll
    for (int j = 0; j < NCLS; j++) o[j] = acc[j];
}

// K7: logits = agg2 + dinv^2*h2 + b2;  out = log_softmax(logits)
__global__ void __launch_bounds__(256) final_kernel(const float* __restrict__ agg2,
                                                    const float* __restrict__ h2,
                                                    const float* __restrict__ dinv,
                                                    const float* __restrict__ b2,
                                                    float* __restrict__ out, int N) {
    __shared__ float bs[NCLS];
    for (int i = threadIdx.x; i < NCLS; i += blockDim.x) bs[i] = b2[i];
    __syncthreads();
    int row = blockIdx.x * blockDim.x + threadIdx.x;
    if (row >= N) return;
    float di = dinv[row];
    float d2 = di * di;
    float l[NCLS];
    const float4* a4 = (const float4*)(agg2 + (size_t)row * NCLS);
    const float4* h4 = (const float4*)(h2 + (size_t)row * NCLS);
#pragma unroll
    for (int q = 0; q < NCLS / 4; q++) {
        float4 a = a4[q];
        float4 hv = h4[q];
        l[4 * q + 0] = a.x + d2 * hv.x + bs[4 * q + 0];
        l[4 * q + 1] = a.y + d2 * hv.y + bs[4 * q + 1];
        l[4 * q + 2] = a.z + d2 * hv.z + bs[4 * q + 2];
        l[4 * q + 3] = a.w + d2 * hv.w + bs[4 * q + 3];
    }
    float m = l[0];
#pragma unroll
    for (int j = 1; j < NCLS; j++) m = fmaxf(m, l[j]);
    float s = 0.0f;
#pragma unroll
    for (int j = 0; j < NCLS; j++) s += expf(l[j] - m);
    float ls = logf(s) + m;
    float* o = out + (size_t)row * NCLS;
#pragma unroll
    for (int j = 0; j < NCLS; j++) o[j] = l[j] - ls;
}

extern "C" void kernel_launch(void* const* d_in, const int* in_sizes, int n_in,
                              void* d_out, int out_size, void* d_ws, size_t ws_size,
                              hipStream_t stream) {
    const float* x  = (const float*)d_in[0];
    const int*   ei = (const int*)d_in[1];
    const float* W1 = (const float*)d_in[2];
    const float* b1 = (const float*)d_in[3];
    const float* W2 = (const float*)d_in[4];
    const float* b2 = (const float*)d_in[5];
    float* out = (float*)d_out;

    const int N = in_sizes[0] / NFEAT;   // 100000
    const int E = in_sizes[1] / 2;       // 3200000

    // workspace layout (floats): [deg/dinv N][agg1 N*24][agg2 N*16][h1 N*24][h2 N*16]
    float* ws   = (float*)d_ws;
    float* dinv = ws;
    float* agg1 = dinv + N;
    float* agg2 = agg1 + (size_t)N * NHID;
    float* h1   = agg2 + (size_t)N * NCLS;
    float* h2   = h1 + (size_t)N * NHID;

    // zero deg + agg1 + agg2 in one contiguous memset
    size_t zero_bytes = ((size_t)N + (size_t)N * NHID + (size_t)N * NCLS) * sizeof(float);
    hipMemsetAsync(d_ws, 0, zero_bytes, stream);

    const int B = 256;
    deg_kernel<<<(E + B - 1) / B, B, 0, stream>>>(ei, dinv, E);
    dinv_kernel<<<(N + B - 1) / B, B, 0, stream>>>(dinv, N);
    gemm1_kernel<<<(N + B - 1) / B, B, 0, stream>>>(x, W1, h1, N);
    agg_kernel<NHID><<<((long long)E * NHID + B - 1) / B, B, 0, stream>>>(ei, dinv, h1, agg1, E);
    fuse2_kernel<<<(N + B - 1) / B, B, 0, stream>>>(agg1, h1, dinv, W2, b1, h2, N);
    agg_kernel<NCLS><<<((long long)E * NCLS + B - 1) / B, B, 0, stream>>>(ei, dinv, h2, agg2, E);
    final_kernel<<<(N + B - 1) / B, B, 0, stream>>>(agg2, h2, dinv, b2, out, N);
}

// Round 2
// 655.270 us; speedup vs baseline: 1.2334x; 1.2334x over previous
//
#include <hip/hip_runtime.h>
#include <math.h>

#define NFEAT 128
#define NHID  24
#define NCLS  16

// ---------------------------------------------------------------------------
// K1: in-degree histogram by dst (row 0 of edge_index)
__global__ void hist_kernel(const int* __restrict__ ei, int* __restrict__ cnt, int E) {
    int e = blockIdx.x * blockDim.x + threadIdx.x;
    if (e < E) atomicAdd(&cnt[ei[e]], 1);
}

// K2: dinv = rsqrt(cnt + 1)   (+1 = self loop)
__global__ void dinv_kernel(const int* __restrict__ cnt, float* __restrict__ dinv, int N) {
    int i = blockIdx.x * blockDim.x + threadIdx.x;
    if (i < N) dinv[i] = rsqrtf((float)cnt[i] + 1.0f);
}

// K3a: per-block exclusive scan of cnt -> row_start (block-local), block totals -> bsum
__global__ void scan1_kernel(const int* __restrict__ cnt, int* __restrict__ rowst,
                             int* __restrict__ bsum, int N) {
    __shared__ int s[256];
    int t = threadIdx.x;
    int i = blockIdx.x * 256 + t;
    int v = (i < N) ? cnt[i] : 0;
    s[t] = v;
    __syncthreads();
    for (int o = 1; o < 256; o <<= 1) {
        int x = (t >= o) ? s[t - o] : 0;
        __syncthreads();
        s[t] += x;
        __syncthreads();
    }
    if (i < N) rowst[i] = s[t] - v;          // exclusive within block
    if (t == 255) bsum[blockIdx.x] = s[255]; // block total
}

// K3b: single-block exclusive scan of block totals (nb <= 512)
__global__ void scan2_kernel(int* __restrict__ bsum, int nb) {
    __shared__ int s[512];
    int t = threadIdx.x;
    int v = (t < nb) ? bsum[t] : 0;
    s[t] = v;
    __syncthreads();
    for (int o = 1; o < 512; o <<= 1) {
        int x = (t >= o) ? s[t - o] : 0;
        __syncthreads();
        s[t] += x;
        __syncthreads();
    }
    if (t < nb) bsum[t] = s[t] - v;
}

// K3c: add block offsets; replicate into cursor for the scatter pass
__global__ void scan3_kernel(int* __restrict__ rowst, int* __restrict__ cursor,
                             const int* __restrict__ bsum, int N) {
    int i = blockIdx.x * 256 + threadIdx.x;
    if (i < N) {
        int r = rowst[i] + bsum[blockIdx.x];
        rowst[i] = r;
        cursor[i] = r;
    }
}

// K4: scatter src ids into CSR adjacency
__global__ void scatter_kernel(const int* __restrict__ ei, int* __restrict__ cursor,
                               int* __restrict__ csr, int E) {
    int e = blockIdx.x * blockDim.x + threadIdx.x;
    if (e < E) {
        int dst = ei[e];
        int src = ei[E + e];
        int p = atomicAdd(&cursor[dst], 1);
        csr[p] = src;
    }
}

// K5: h1s = dinv[row] * (x @ W1); W1 staged in LDS (12 KB)
__global__ void __launch_bounds__(256) gemm1_kernel(const float* __restrict__ x,
                                                    const float* __restrict__ W1,
                                                    const float* __restrict__ dinv,
                                                    float* __restrict__ h1s, int N) {
    __shared__ float w[NFEAT * NHID];
    for (int i = threadIdx.x; i < NFEAT * NHID; i += blockDim.x) w[i] = W1[i];
    __syncthreads();
    int row = blockIdx.x * blockDim.x + threadIdx.x;
    if (row >= N) return;
    float acc[NHID];
#pragma unroll
    for (int j = 0; j < NHID; j++) acc[j] = 0.0f;
    const float4* xr = (const float4*)(x + (size_t)row * NFEAT);
    for (int k4 = 0; k4 < NFEAT / 4; k4++) {
        float4 v = xr[k4];
        const float* wr = &w[k4 * 4 * NHID];
#pragma unroll
        for (int j = 0; j < NHID; j++) acc[j] += v.x * wr[j];
#pragma unroll
        for (int j = 0; j < NHID; j++) acc[j] += v.y * wr[NHID + j];
#pragma unroll
        for (int j = 0; j < NHID; j++) acc[j] += v.z * wr[2 * NHID + j];
#pragma unroll
        for (int j = 0; j < NHID; j++) acc[j] += v.w * wr[3 * NHID + j];
    }
    float di = dinv[row];
    float* o = h1s + (size_t)row * NHID;
#pragma unroll
    for (int j = 0; j < NHID; j++) o[j] = di * acc[j];
}

// K6: layer-1 aggregation over CSR + fused self-loop/bias/relu
//     hrelu[n,f] = relu( dinv[n] * (sum_{src in in(n)} h1s[src,f] + h1s[n,f]) + b1[f] )
//     24 lanes per node, 8 nodes per 192-thread block; 4-way unrolled gathers.
__global__ void __launch_bounds__(192) agg1_kernel(const int* __restrict__ csr,
                                                   const int* __restrict__ rowst,
                                                   const int* __restrict__ cnt,
                                                   const float* __restrict__ h1s,
                                                   const float* __restrict__ dinv,
                                                   const float* __restrict__ b1,
                                                   float* __restrict__ hrelu, int N) {
    int g = threadIdx.x / NHID;
    int f = threadIdx.x - g * NHID;
    int node = blockIdx.x * 8 + g;
    if (node >= N) return;
    int st = rowst[node];
    int dg = cnt[node];
    float a0 = 0.f, a1 = 0.f, a2 = 0.f, a3 = 0.f;
    int e = 0;
    for (; e + 4 <= dg; e += 4) {
        int s0 = csr[st + e];
        int s1 = csr[st + e + 1];
        int s2 = csr[st + e + 2];
        int s3 = csr[st + e + 3];
        a0 += h1s[s0 * NHID + f];
        a1 += h1s[s1 * NHID + f];
        a2 += h1s[s2 * NHID + f];
        a3 += h1s[s3 * NHID + f];
    }
    for (; e < dg; e++) a0 += h1s[csr[st + e] * NHID + f];
    float sum = (a0 + a1) + (a2 + a3);
    float v = dinv[node] * (sum + h1s[node * NHID + f]) + b1[f];
    hrelu[node * NHID + f] = fmaxf(v, 0.0f);
}

// K7: h2s = dinv[row] * (hrelu @ W2)   (24 -> 16, W2 in LDS)
__global__ void __launch_bounds__(256) fuse2_kernel(const float* __restrict__ hrelu,
                                                    const float* __restrict__ dinv,
                                                    const float* __restrict__ W2,
                                                    float* __restrict__ h2s, int N) {
    __shared__ float w[NHID * NCLS];
    for (int i = threadIdx.x; i < NHID * NCLS; i += blockDim.x) w[i] = W2[i];
    __syncthreads();
    int row = blockIdx.x * blockDim.x + threadIdx.x;
    if (row >= N) return;
    float hr[NHID];
    const float4* h4 = (const float4*)(hrelu + (size_t)row * NHID);
#pragma unroll
    for (int q = 0; q < NHID / 4; q++) {
        float4 hv = h4[q];
        hr[4 * q + 0] = hv.x;
        hr[4 * q + 1] = hv.y;
        hr[4 * q + 2] = hv.z;
        hr[4 * q + 3] = hv.w;
    }
    float acc[NCLS];
#pragma unroll
    for (int j = 0; j < NCLS; j++) acc[j] = 0.0f;
#pragma unroll
    for (int k = 0; k < NHID; k++) {
#pragma unroll
        for (int j = 0; j < NCLS; j++) acc[j] += hr[k] * w[k * NCLS + j];
    }
    float di = dinv[row];
    float* o = h2s + (size_t)row * NCLS;
#pragma unroll
    for (int j = 0; j < NCLS; j++) o[j] = di * acc[j];
}

// K8: layer-2 aggregation + self-loop + b2 + log_softmax (16-lane shuffle butterfly)
//     16 lanes per node, 16 nodes per 256-thread block.
__global__ void __launch_bounds__(256) agg2_kernel(const int* __restrict__ csr,
                                                   const int* __restrict__ rowst,
                                                   const int* __restrict__ cnt,
                                                   const float* __restrict__ h2s,
                                                   const float* __restrict__ dinv,
                                                   const float* __restrict__ b2,
                                                   float* __restrict__ out, int N) {
    int g = threadIdx.x >> 4;
    int f = threadIdx.x & 15;
    int node = blockIdx.x * 16 + g;
    if (node >= N) return;
    int st = rowst[node];
    int dg = cnt[node];
    float a0 = 0.f, a1 = 0.f, a2 = 0.f, a3 = 0.f;
    int e = 0;
    for (; e + 4 <= dg; e += 4) {
        int s0 = csr[st + e];
        int s1 = csr[st + e + 1];
        int s2 = csr[st + e + 2];
        int s3 = csr[st + e + 3];
        a0 += h2s[s0 * NCLS + f];
        a1 += h2s[s1 * NCLS + f];
        a2 += h2s[s2 * NCLS + f];
        a3 += h2s[s3 * NCLS + f];
    }
    for (; e < dg; e++) a0 += h2s[csr[st + e] * NCLS + f];
    float sum = (a0 + a1) + (a2 + a3);
    float l = dinv[node] * (sum + h2s[node * NCLS + f]) + b2[f];
    // log_softmax across the 16 lanes of this group (lane-aligned within a wave)
    float m = l;
#pragma unroll
    for (int o = 1; o < 16; o <<= 1) m = fmaxf(m, __shfl_xor(m, o, 16));
    float ex = expf(l - m);
    float ssum = ex;
#pragma unroll
    for (int o = 1; o < 16; o <<= 1) ssum += __shfl_xor(ssum, o, 16);
    out[node * NCLS + f] = l - (logf(ssum) + m);
}

extern "C" void kernel_launch(void* const* d_in, const int* in_sizes, int n_in,
                              void* d_out, int out_size, void* d_ws, size_t ws_size,
                              hipStream_t stream) {
    const float* x  = (const float*)d_in[0];
    const int*   ei = (const int*)d_in[1];
    const float* W1 = (const float*)d_in[2];
    const float* b1 = (const float*)d_in[3];
    const float* W2 = (const float*)d_in[4];
    const float* b2 = (const float*)d_in[5];
    float* out = (float*)d_out;

    const int N = in_sizes[0] / NFEAT;   // 100000
    const int E = in_sizes[1] / 2;       // 3200000

    // workspace layout: [cnt N][rowst N][cursor N][bsum 512][csr E] ints,
    // then [dinv N][h1s 24N][hrelu 24N] floats; h2s aliases h1s (dead after agg1).
    int* cnt    = (int*)d_ws;
    int* rowst  = cnt + N;
    int* cursor = rowst + N;
    int* bsum   = cursor + N;
    int* csr    = bsum + 512;
    float* dinv  = (float*)(csr + E);
    float* h1s   = dinv + N;
    float* hrelu = h1s + (size_t)N * NHID;
    float* h2s   = h1s;  // alias: h1s dead after agg1; fuse2 reads hrelu, writes h2s

    hipMemsetAsync(cnt, 0, (size_t)N * sizeof(int), stream);

    const int B = 256;
    const int nb = (N + B - 1) / B;  // 391 scan blocks (<= 512)
    hist_kernel<<<(E + B - 1) / B, B, 0, stream>>>(ei, cnt, E);
    dinv_kernel<<<nb, B, 0, stream>>>(cnt, dinv, N);
    scan1_kernel<<<nb, B, 0, stream>>>(cnt, rowst, bsum, N);
    scan2_kernel<<<1, 512, 0, stream>>>(bsum, nb);
    scan3_kernel<<<nb, B, 0, stream>>>(rowst, cursor, bsum, N);
    scatter_kernel<<<(E + B - 1) / B, B, 0, stream>>>(ei, cursor, csr, E);
    gemm1_kernel<<<nb, B, 0, stream>>>(x, W1, dinv, h1s, N);
    agg1_kernel<<<(N + 7) / 8, 192, 0, stream>>>(csr, rowst, cnt, h1s, dinv, b1, hrelu, N);
    fuse2_kernel<<<nb, B, 0, stream>>>(hrelu, dinv, W2, h2s, N);
    agg2_kernel<<<(N + 15) / 16, B, 0, stream>>>(csr, rowst, cnt, h2s, dinv, b2, out, N);
}